// Round 3
// baseline (308.226 us; speedup 1.0000x reference)
//
#include <hip/hip_runtime.h>

// ---------------------------------------------------------------------------
// CrossAttention_LocalAVTokens: bs=32, nmm=256, nv+na=256, DIM=768, H=12, hd=64.
// Outputs: out [32,256,768] f32, attn [32,12,256,256] f32.
// Round 3: KV GEMM emits V^T directly; attention is staging-free (direct-global
// MFMA operands, wave-private P strip in LDS, no __syncthreads), 3 WG/CU.
// ---------------------------------------------------------------------------

typedef __attribute__((ext_vector_type(8))) _Float16 f16x8;
typedef __attribute__((ext_vector_type(4))) _Float16 f16x4;
typedef __attribute__((ext_vector_type(4))) float    f32x4;

#define AS1 __attribute__((address_space(1)))
#define AS3 __attribute__((address_space(3)))

__device__ __forceinline__ void gload_lds16(const void* g, void* l) {
    __builtin_amdgcn_global_load_lds((AS1 void*)const_cast<void*>(g), (AS3 void*)l, 16, 0, 0);
}

// ---------------------------------------------------------------------------
// prep_all: xmm->f16, concat[xv;xa]->f16 (float4 granular), then the three
// weight transposes (scalar; L2 absorbs the strided reads). One launch.
// ---------------------------------------------------------------------------
__global__ __launch_bounds__(256) void prep_all(const float* __restrict__ xmm,
                                                const float* __restrict__ xv,
                                                const float* __restrict__ xa,
                                                const float* __restrict__ Wq,
                                                const float* __restrict__ Wkv,
                                                const float* __restrict__ Wproj,
                                                _Float16* __restrict__ xmm16,
                                                _Float16* __restrict__ xsrc16,
                                                _Float16* __restrict__ WqT,
                                                _Float16* __restrict__ WkvT,
                                                _Float16* __restrict__ WprojT) {
    int id = blockIdx.x * 256 + threadIdx.x;
    if (id < 3145728) {                        // activation casts, float4 units
        float4 v;
        _Float16* dst; int off;
        if (id < 1572864) {
            v = ((const float4*)xmm)[id];
            dst = xmm16; off = id;
        } else {
            int t = id - 1572864;
            int c4 = t % 192;
            int r  = (t / 192) & 255;
            int b  = t / 49152;
            if (r < 196) v = ((const float4*)xv)[((long)b * 196 + r) * 192 + c4];
            else         v = ((const float4*)xa)[((long)b * 60 + (r - 196)) * 192 + c4];
            dst = xsrc16; off = t;
        }
        f16x4 h = { (_Float16)v.x, (_Float16)v.y, (_Float16)v.z, (_Float16)v.w };
        ((f16x4*)dst)[off] = h;
        return;
    }
    id -= 3145728;
    if (id < 589824) {            // WqT [768n][768k] = 0.125 * Wq[k][n]  (scale folded)
        int k = id % 768, n = id / 768;
        WqT[id] = (_Float16)(0.125f * Wq[(long)k * 768 + n]);
        return;
    }
    id -= 589824;
    if (id < 1179648) {           // WkvT [1536n][768k]
        int k = id % 768, n = id / 768;
        WkvT[id] = (_Float16)Wkv[(long)k * 1536 + n];
        return;
    }
    id -= 1179648;
    if (id < 589824) {            // WprojT [768n][768k]
        int k = id % 768, n = id / 768;
        WprojT[id] = (_Float16)Wproj[(long)k * 768 + n];
    }
}

// ---------------------------------------------------------------------------
// GEMM body: C = A[M,K] @ Bt[N,K]^T, 128x128 tile, BK=64, 4 waves.
// EPI 0: f16 row-major (swapped mfma -> lane holds 4 consecutive cols)
// EPI 1: f32 + bias row-major (swapped)
// EPI 2: f16 transposed V^T store (plain mfma -> lane holds 4 consecutive rows);
//        C is Vt16 [32*768][256]: element (m,n) -> Vt[((m>>8)*768 + bn+n)*256 + (m&255)]
// ---------------------------------------------------------------------------
enum { EPI_F16_ROW = 0, EPI_F32_BIAS = 1, EPI_F16_VT = 2 };

template <int EPI>
__device__ __forceinline__ void gemm_body(const _Float16* __restrict__ A,
                                          const _Float16* __restrict__ Bt,
                                          void* __restrict__ C,
                                          const float* __restrict__ bias,
                                          long bm, long bn, int N, int K) {
    __shared__ _Float16 As[128 * 64];
    __shared__ _Float16 Bs[128 * 64];

    const int tid  = threadIdx.x;
    const int wave = tid >> 6, lane = tid & 63;
    const int lrow = lane & 15, quad = lane >> 4;
    const int wm = (wave >> 1) * 64, wn = (wave & 1) * 64;

    f32x4 acc[4][4];
    const f32x4 fz = {0.f, 0.f, 0.f, 0.f};
#pragma unroll
    for (int mt = 0; mt < 4; ++mt)
#pragma unroll
        for (int nt = 0; nt < 4; ++nt) acc[mt][nt] = fz;

    for (int k0 = 0; k0 < K; k0 += 64) {
#pragma unroll
        for (int it = 0; it < 4; ++it) {
            int seg = tid + it * 256;                 // 1024 segs of 8 halves
            int rr = seg >> 3, pp = seg & 7;
            int cc = ((pp ^ (rr & 7)) << 3);          // swizzled source column
            gload_lds16(A  + (bm + rr) * (long)K + k0 + cc, As + seg * 8);
            gload_lds16(Bt + (bn + rr) * (long)K + k0 + cc, Bs + seg * 8);
        }
        __syncthreads();
#pragma unroll
        for (int ks = 0; ks < 2; ++ks) {
            f16x8 af[4], bf[4];
#pragma unroll
            for (int mt = 0; mt < 4; ++mt) {
                int r = wm + mt * 16 + lrow;
                af[mt] = *(const f16x8*)(As + r * 64 + (((ks * 4 + quad) ^ (r & 7)) << 3));
            }
#pragma unroll
            for (int nt = 0; nt < 4; ++nt) {
                int r = wn + nt * 16 + lrow;
                bf[nt] = *(const f16x8*)(Bs + r * 64 + (((ks * 4 + quad) ^ (r & 7)) << 3));
            }
#pragma unroll
            for (int mt = 0; mt < 4; ++mt)
#pragma unroll
                for (int nt = 0; nt < 4; ++nt) {
                    if (EPI == EPI_F16_VT)
                        acc[mt][nt] = __builtin_amdgcn_mfma_f32_16x16x32_f16(
                            af[mt], bf[nt], acc[mt][nt], 0, 0, 0);   // plain: rows per lane
                    else
                        acc[mt][nt] = __builtin_amdgcn_mfma_f32_16x16x32_f16(
                            bf[nt], af[mt], acc[mt][nt], 0, 0, 0);   // swapped: cols per lane
                }
        }
        __syncthreads();
    }

    if (EPI == EPI_F16_VT) {
        // lane owns rows m = bm+wm+mt*16+quad*4+{0..3}, col n = wn+nt*16+lrow
        const long b = bm >> 8;
        const int key0 = (int)(bm & 255);
#pragma unroll
        for (int mt = 0; mt < 4; ++mt) {
            int key = key0 + wm + mt * 16 + quad * 4;
#pragma unroll
            for (int nt = 0; nt < 4; ++nt) {
                long nd = bn + wn + nt * 16 + lrow;
                f16x4 h = { (_Float16)acc[mt][nt][0], (_Float16)acc[mt][nt][1],
                            (_Float16)acc[mt][nt][2], (_Float16)acc[mt][nt][3] };
                *(f16x4*)((_Float16*)C + (b * 768 + nd) * 256 + key) = h;
            }
        }
    } else {
        // lane owns C[bm+wm+mt*16+lrow][bn+wn+nt*16+quad*4 + 0..3]
#pragma unroll
        for (int mt = 0; mt < 4; ++mt) {
            long row = bm + wm + mt * 16 + lrow;
#pragma unroll
            for (int nt = 0; nt < 4; ++nt) {
                long col0 = bn + wn + nt * 16 + quad * 4;
                if (EPI == EPI_F32_BIAS) {
                    float4 b4 = *(const float4*)(bias + col0);
                    float4 o = { acc[mt][nt][0] + b4.x, acc[mt][nt][1] + b4.y,
                                 acc[mt][nt][2] + b4.z, acc[mt][nt][3] + b4.w };
                    *(float4*)((float*)C + row * N + col0) = o;
                } else {
                    f16x4 h = { (_Float16)acc[mt][nt][0], (_Float16)acc[mt][nt][1],
                                (_Float16)acc[mt][nt][2], (_Float16)acc[mt][nt][3] };
                    *(f16x4*)((_Float16*)C + row * N + col0) = h;
                }
            }
        }
    }
}

// Merged Q + K + V^T projections: grid (18, 64).
__global__ __launch_bounds__(256, 2)
void gemm_qkv(const _Float16* __restrict__ xmm16, const _Float16* __restrict__ xsrc16,
              const _Float16* __restrict__ WqT, const _Float16* __restrict__ WkvT,
              _Float16* __restrict__ Q16, _Float16* __restrict__ K16,
              _Float16* __restrict__ Vt16) {
    const int bx = blockIdx.x;
    const long bm = (long)blockIdx.y * 128;
    if (bx < 6)
        gemm_body<EPI_F16_ROW>(xmm16, WqT, (void*)Q16, nullptr, bm, (long)bx * 128, 768, 768);
    else if (bx < 12)
        gemm_body<EPI_F16_ROW>(xsrc16, WkvT, (void*)K16, nullptr, bm, (long)(bx - 6) * 128, 768, 768);
    else
        gemm_body<EPI_F16_VT>(xsrc16, WkvT + 768L * 768, (void*)Vt16, nullptr, bm, (long)(bx - 12) * 128, 256, 768);
}

// Output projection (+bias), f32 out. grid (6, 64).
__global__ __launch_bounds__(256, 2)
void gemm_proj(const _Float16* __restrict__ O16, const _Float16* __restrict__ WprojT,
               float* __restrict__ out, const float* __restrict__ bias) {
    gemm_body<EPI_F32_BIAS>(O16, WprojT, (void*)out, bias,
                            (long)blockIdx.y * 128, (long)blockIdx.x * 128, 768, 768);
}

// ---------------------------------------------------------------------------
// Attention, staging-free. Grid (4 qb, 12 h, 32 b), 256 thr.
// S^T = K Q^T via mfma(bk, aq), both operands direct from global (each wave's
// quads cover contiguous 64B per row; slices are L2-resident). Softmax with 2
// shuffles. P staged in a wave-private swizzled LDS strip (no barrier), then
// O = P V via mfma(bv, ap) with V^T fragments direct from global Vt16.
// ---------------------------------------------------------------------------
__global__ __launch_bounds__(256, 3)
void attn_kernel(const _Float16* __restrict__ Qg, const _Float16* __restrict__ Kg,
                 const _Float16* __restrict__ Vt, float* __restrict__ attn_out,
                 _Float16* __restrict__ Og) {
    __shared__ _Float16 Ps[64 * 256];   // 32 KB; wave w owns rows [16w,16w+16)

    const int tid  = threadIdx.x;
    const int wave = tid >> 6, lane = tid & 63;
    const int lrow = lane & 15, quad = lane >> 4;
    const int qb = blockIdx.x, h = blockIdx.y, b = blockIdx.z;
    const long qrow0 = (long)b * 256 + qb * 64;
    const long krow0 = (long)b * 256;
    const long vbase = ((long)b * 768 + h * 64) * 256;

    // Q fragments (B-operand of swapped mfma: col=lane&15 -> q, k=quad*8+j)
    f16x8 aq[2];
#pragma unroll
    for (int ks = 0; ks < 2; ++ks)
        aq[ks] = *(const f16x8*)(Qg + (qrow0 + wave * 16 + lrow) * 768 + h * 64 + ks * 32 + quad * 8);

    // S^T: lane holds q = wave*16+lrow fixed, keys nt*16+quad*4+{0..3}
    f32x4 sacc[16];
    const f32x4 fz = {0.f, 0.f, 0.f, 0.f};
#pragma unroll
    for (int nt = 0; nt < 16; ++nt) sacc[nt] = fz;
#pragma unroll
    for (int ks = 0; ks < 2; ++ks) {
#pragma unroll
        for (int nt = 0; nt < 16; ++nt) {
            f16x8 bk = *(const f16x8*)(Kg + (krow0 + nt * 16 + lrow) * 768 + h * 64 + ks * 32 + quad * 8);
            sacc[nt] = __builtin_amdgcn_mfma_f32_16x16x32_f16(bk, aq[ks], sacc[nt], 0, 0, 0);
        }
    }

    // softmax over keys for q = wave*16+lrow (scale already folded into Wq)
    float m = -1e30f;
#pragma unroll
    for (int nt = 0; nt < 16; ++nt)
#pragma unroll
        for (int j = 0; j < 4; ++j) m = fmaxf(m, sacc[nt][j]);
    m = fmaxf(m, __shfl_xor(m, 16));
    m = fmaxf(m, __shfl_xor(m, 32));
    float s = 0.f;
#pragma unroll
    for (int nt = 0; nt < 16; ++nt)
#pragma unroll
        for (int j = 0; j < 4; ++j) {
            float p = __expf(sacc[nt][j] - m);
            sacc[nt][j] = p; s += p;
        }
    s += __shfl_xor(s, 16);
    s += __shfl_xor(s, 32);
    const float li = 1.f / s;

    // attn store (float4) + normalized P into wave-private swizzled LDS strip
    const long abase = (((long)b * 12 + h) * 256 + qb * 64) * 256;
    const int q = wave * 16 + lrow;
#pragma unroll
    for (int nt = 0; nt < 16; ++nt) {
        float4 o = { sacc[nt][0] * li, sacc[nt][1] * li, sacc[nt][2] * li, sacc[nt][3] * li };
        *(float4*)(attn_out + abase + (long)q * 256 + nt * 16 + quad * 4) = o;
        f16x4 hp = { (_Float16)o.x, (_Float16)o.y, (_Float16)o.z, (_Float16)o.w };
        int key  = nt * 16 + quad * 4;
        int phys = (key >> 3) ^ (q & 31);                     // 16B-block swizzle
        *(f16x4*)(Ps + q * 256 + (phys << 3) + (key & 7)) = hp;
    }
    // wave-private LDS strip: only need this wave's DS writes complete
    __asm__ __volatile__("s_waitcnt lgkmcnt(0)" ::: "memory");

    // O = P V: lane holds q = wave*16+lrow, d = nt*16+quad*4+{0..3}
    f32x4 oacc[4];
#pragma unroll
    for (int nt = 0; nt < 4; ++nt) oacc[nt] = fz;
#pragma unroll
    for (int ks = 0; ks < 8; ++ks) {
        int kq = ks * 4 + quad;                               // logical 16B block
        f16x8 ap = *(const f16x8*)(Ps + q * 256 + ((kq ^ (q & 31)) << 3));
#pragma unroll
        for (int nt = 0; nt < 4; ++nt) {
            f16x8 bv = *(const f16x8*)(Vt + vbase + (nt * 16 + lrow) * 256 + ks * 32 + quad * 8);
            oacc[nt] = __builtin_amdgcn_mfma_f32_16x16x32_f16(bv, ap, oacc[nt], 0, 0, 0);
        }
    }
#pragma unroll
    for (int nt = 0; nt < 4; ++nt) {
        f16x4 ho = { (_Float16)oacc[nt][0], (_Float16)oacc[nt][1],
                     (_Float16)oacc[nt][2], (_Float16)oacc[nt][3] };
        *(f16x4*)(Og + (qrow0 + wave * 16 + lrow) * 768 + h * 64 + nt * 16 + quad * 4) = ho;
    }
}

// ---------------------------------------------------------------------------
extern "C" void kernel_launch(void* const* d_in, const int* in_sizes, int n_in,
                              void* d_out, int out_size, void* d_ws, size_t ws_size,
                              hipStream_t stream) {
    const float* xmm   = (const float*)d_in[0];
    const float* xv    = (const float*)d_in[1];
    const float* xa    = (const float*)d_in[2];
    const float* Wq    = (const float*)d_in[3];
    const float* Wkv   = (const float*)d_in[4];
    const float* Wproj = (const float*)d_in[5];
    const float* bproj = (const float*)d_in[6];

    float* out  = (float*)d_out;            // [32,256,768]
    float* attn = out + 6291456;            // [32,12,256,256]

    char* ws = (char*)d_ws;
    _Float16* xmm16  = (_Float16*)(ws);                   // 12,582,912 B
    _Float16* xsrc16 = (_Float16*)(ws + 12582912);        // 12,582,912 B
    _Float16* WqT    = (_Float16*)(ws + 25165824);        //  1,179,648 B
    _Float16* WkvT   = (_Float16*)(ws + 26345472);        //  2,359,296 B
    _Float16* WprojT = (_Float16*)(ws + 28704768);        //  1,179,648 B
    _Float16* Q16    = (_Float16*)(ws + 29884416);        // 12,582,912 B
    _Float16* K16    = (_Float16*)(ws + 42467328);        // 12,582,912 B
    _Float16* Vt16   = (_Float16*)(ws + 55050240);        // 12,582,912 B -> 67,633,152 total
    _Float16* O16    = xmm16;   // xmm16 dead after QKV GEMM; reuse for O

    prep_all<<<21504, 256, 0, stream>>>(xmm, xv, xa, Wq, Wkv, Wproj,
                                        xmm16, xsrc16, WqT, WkvT, WprojT);

    gemm_qkv<<<dim3(18, 64), 256, 0, stream>>>(xmm16, xsrc16, WqT, WkvT, Q16, K16, Vt16);

    attn_kernel<<<dim3(4, 12, 32), 256, 0, stream>>>(Q16, K16, Vt16, attn, O16);

    gemm_proj<<<dim3(6, 64), 256, 0, stream>>>(O16, WprojT, out, bproj);
}